// Round 2
// baseline (590.192 us; speedup 1.0000x reference)
//
#include <hip/hip_runtime.h>
#include <hip/hip_bf16.h>

// FlyLoRALinear fused: out = (topk8-mask(|x@A^T + d|) * (x@A^T)) @ B^T * 2
// x:[4,4096,4096]f32  A:[32,4096]f32  B:[4096,32]f32  d:[32]f32  out:[4,4096,4096]f32
#define IN_F   4096
#define RDIM   32
#define KSEL   8
#define OUT_F  4096

typedef float  f4 __attribute__((ext_vector_type(4)));
typedef short  s8 __attribute__((ext_vector_type(8)));   // bf16x8 MFMA frag
typedef float  cf4 __attribute__((ext_vector_type(4)));  // MFMA accum

__device__ inline short f2bf(float f) {
  __hip_bfloat16 h = __float2bfloat16(f);
  return *reinterpret_cast<short*>(&h);
}

// async global->LDS DMA, 16 B per lane. LDS dest must be wave-uniform base
// + lane*16 (it is: our staging layout is lane-contiguous within each wave).
__device__ inline void glds16(const float* g, float* l) {
  __builtin_amdgcn_global_load_lds(
      (const __attribute__((address_space(1))) void*)g,
      (__attribute__((address_space(3))) void*)l, 16, 0, 0);
}

// ---------------- k0: B fp32 -> bf16 (4096x32 elems, 8/thread) --------------
__global__ __launch_bounds__(256) void k0_convB(const float* __restrict__ B,
                                                short* __restrict__ Bb) {
  int idx = blockIdx.x * 256 + threadIdx.x;     // 0..16383
  const f4* p = (const f4*)(B + (size_t)idx * 8);
  f4 v0 = p[0], v1 = p[1];
  s8 o;
  o[0] = f2bf(v0.x); o[1] = f2bf(v0.y); o[2] = f2bf(v0.z); o[3] = f2bf(v0.w);
  o[4] = f2bf(v1.x); o[5] = f2bf(v1.y); o[6] = f2bf(v1.z); o[7] = f2bf(v1.w);
  *(s8*)(Bb + (size_t)idx * 8) = o;
}

// ---------------- fused: project(fp32) + top8 + LoRA-GEMM(MFMA) -------------
// 1024 WGs x 256 thr; WG = 16 tokens (two 8-token passes).
// Phase A (x2): y = x@A^T. Wave w owns r=8w..8w+7; lanes split K 64-way.
//   x staged 512-float chunks via double-buffered global_load_lds (prefetch
//   issued AFTER the barrier so the vmcnt drain doesn't eat the prefetch).
//   A read from global (L2-hot: 512 KB, ~1 GB aggregate L2 traffic ~ 29 us).
// Phase B: fp64 cross-lane reduce -> |y+d| rank-top8 -> Z bf16 in LDS (x2 scale folded).
// Phase C: out[16][4096] = Z @ Bb^T via mfma 16x16x32 bf16, streaming stores.
__global__ __launch_bounds__(256, 3) void k_fused(
    const float* __restrict__ x, const float* __restrict__ A,
    const float* __restrict__ dbias, const short* __restrict__ Bb,
    float* __restrict__ out)
{
  // smem: staging xs[2][8*512] (floats 0..8192) ALIASED with reduction
  // scratch red[4 waves][32 accs][stride 66] (8448 floats). 33 KB.
  __shared__ __align__(16) float smem[8448];
  __shared__ double score[16][RDIM];   // 4 KB
  __shared__ float  yval[16][RDIM];    // 2 KB
  __shared__ __align__(16) short zs[16 * RDIM];  // 1 KB, bf16 Z

  const int tid  = threadIdx.x;
  const int lane = tid & 63;
  const int w    = tid >> 6;
  const int m0   = blockIdx.x * 16;

  const float* Abase = A + (size_t)(8 * w) * IN_F;

  // staging geometry: rep in 0..3, flat = rep*256+tid -> t = flat>>7 (wave-
  // uniform), pos = (flat&127)*4 -> per-wave 1 KB contiguous on both sides.
  const int sflat_t[4] = {(0*256 + tid) >> 7, (1*256 + tid) >> 7,
                          (2*256 + tid) >> 7, (3*256 + tid) >> 7};
  const int sflat_p = (tid & 127) << 2;   // same low-7 bits for every rep

  for (int p = 0; p < 2; ++p) {
    const int tm0 = m0 + 8 * p;

    float acc[8][8];
    #pragma unroll
    for (int t = 0; t < 8; ++t)
      #pragma unroll
      for (int j = 0; j < 8; ++j) acc[t][j] = 0.f;

    // prefetch chunk 0 into buf0
    #pragma unroll
    for (int rep = 0; rep < 4; ++rep)
      glds16(x + (size_t)(tm0 + sflat_t[rep]) * IN_F + sflat_p,
             smem + sflat_t[rep] * 512 + sflat_p);

    for (int c = 0; c < 8; ++c) {
      const int kbase = c * 512;
      float* buf = smem + (c & 1) * 4096;
      __syncthreads();                  // drain: chunk c resident in LDS
      if (c < 7) {                      // prefetch c+1 into the other buffer
        const int kn = (c + 1) * 512;
        float* nbuf = smem + ((c + 1) & 1) * 4096;
        #pragma unroll
        for (int rep = 0; rep < 4; ++rep)
          glds16(x + (size_t)(tm0 + sflat_t[rep]) * IN_F + kn + sflat_p,
                 nbuf + sflat_t[rep] * 512 + sflat_p);
      }
      #pragma unroll
      for (int i = 0; i < 2; ++i) {
        const int kk = 256 * i + 4 * lane;
        f4 av[8];
        #pragma unroll
        for (int j = 0; j < 8; ++j)
          av[j] = *(const f4*)(Abase + (size_t)j * IN_F + kbase + kk);
        #pragma unroll
        for (int t = 0; t < 8; ++t) {
          f4 xv = *(const f4*)&buf[t * 512 + kk];
          #pragma unroll
          for (int j = 0; j < 8; ++j) {
            acc[t][j] = fmaf(xv.x, av[j].x, acc[t][j]);
            acc[t][j] = fmaf(xv.y, av[j].y, acc[t][j]);
            acc[t][j] = fmaf(xv.z, av[j].z, acc[t][j]);
            acc[t][j] = fmaf(xv.w, av[j].w, acc[t][j]);
          }
        }
      }
    }
    __syncthreads();                    // staging buffers dead -> red scratch

    // cross-lane reduce: 2 rounds x 32 accs. stride 66 -> 2-way banks (free).
    // fp64 final sum: top-k ordering must be exact (flips are fatal).
    float* red = smem + w * 2112;
    #pragma unroll
    for (int h = 0; h < 2; ++h) {
      #pragma unroll
      for (int a = 0; a < 32; ++a)
        red[a * 66 + lane] = acc[4 * h + (a >> 3)][a & 7];
      __syncthreads();
      if (lane < 32) {
        double s = 0.0;
        #pragma unroll
        for (int m = 0; m < 64; ++m) s += (double)red[lane * 66 + m];
        int t = 8 * p + 4 * h + (lane >> 3);
        int r = 8 * w + (lane & 7);
        double b = s + (double)dbias[r];
        score[t][r] = fabs(b);
        yval[t][r]  = (float)s;
      }
      __syncthreads();
    }
  }

  // Phase B: rank-based top-8 (== jax.lax.top_k incl. lower-index tie-break).
  #pragma unroll
  for (int e = 0; e < 2; ++e) {
    int idx = e * 256 + tid;            // 0..511 = 16 tok x 32 r
    int t = idx >> 5, i = idx & 31;
    double si = score[t][i];
    int rank = 0;
    #pragma unroll
    for (int j = 0; j < RDIM; ++j) {
      double sj = score[t][j];
      rank += (sj > si) || (sj == si && j < i);
    }
    float z = (rank < KSEL) ? yval[t][i] * 2.0f : 0.0f;  // fold SCALE=2
    zs[t * RDIM + i] = f2bf(z);
  }
  __syncthreads();

  // Phase C: out[m0..m0+16) = Z @ Bb^T. Wave w covers cols [1024w, 1024w+1024).
  {
    const int rr = lane & 15;           // A-frag row (token) / D col
    const int q  = lane >> 4;           // k-block 8q..8q+7 / D row group
    s8 a = *(const s8*)(zs + rr * RDIM + q * 8);
    const short* Bp = Bb + (size_t)(w * 1024 + rr) * RDIM + q * 8;
    float* op = out + (size_t)(m0 + q * 4) * OUT_F + w * 1024 + rr;
    #pragma unroll 8
    for (int tile = 0; tile < 64; ++tile) {
      s8 b = *(const s8*)(Bp + (size_t)tile * 16 * RDIM);
      cf4 d = {0.f, 0.f, 0.f, 0.f};
      d = __builtin_amdgcn_mfma_f32_16x16x32_bf16(a, b, d, 0, 0, 0);
      // D: col = lane&15 (o-col), row = 4q+reg (token)
      #pragma unroll
      for (int reg = 0; reg < 4; ++reg)
        __builtin_nontemporal_store(d[reg], op + (size_t)reg * OUT_F + tile * 16);
    }
  }
}

extern "C" void kernel_launch(void* const* d_in, const int* in_sizes, int n_in,
                              void* d_out, int out_size, void* d_ws, size_t ws_size,
                              hipStream_t stream) {
  const float* x     = (const float*)d_in[0];
  const float* A     = (const float*)d_in[1];
  const float* B     = (const float*)d_in[2];
  const float* dbias = (const float*)d_in[3];
  float* out = (float*)d_out;

  short* Bb = (short*)d_ws;                          // 4096*32 bf16 = 256 KB

  hipLaunchKernelGGL(k0_convB, dim3(64),   dim3(256), 0, stream, B, Bb);
  hipLaunchKernelGGL(k_fused,  dim3(1024), dim3(256), 0, stream,
                     x, A, dbias, Bb, out);
}